// Round 4
// baseline (195.094 us; speedup 1.0000x reference)
//
#include <hip/hip_runtime.h>

typedef unsigned short u16;
typedef unsigned int   u32;
typedef __attribute__((ext_vector_type(8))) short short8;   // 8 bf16 = 4 VGPRs
typedef __attribute__((ext_vector_type(4))) float f32x4;

#define NB    4      // batch
#define NCH   256    // channels
#define NHD   8      // heads
#define HD    32     // head dim
#define NSP   2304   // H*W
#define NBH   32     // NB*NHD
#define NKT   36     // total 64-wide K tiles
#define KPW   9      // K tiles per wave (4-wave in-block k-split)

// round-to-nearest-even fp32 -> bf16 bits
__device__ __forceinline__ u16 f2bf(float f) {
    u32 u = __float_as_uint(f);
    u += 0x7FFFu + ((u >> 16) & 1u);
    return (u16)(u >> 16);
}
__device__ __forceinline__ u32 pack2(float a, float b) {
    return (u32)f2bf(a) | ((u32)f2bf(b) << 16);
}
// fast pack two fp32 -> bf16x2: hw cvt (RNE) if present, else 1-instr v_perm truncate.
__device__ __forceinline__ u32 pkfast(float a, float b) {
#if __has_builtin(__builtin_amdgcn_cvt_pk_bf16_f32)
    typedef __attribute__((ext_vector_type(2))) __bf16 bf2;
    union { bf2 v; u32 u; } cv;
    cv.v = __builtin_amdgcn_cvt_pk_bf16_f32(a, b);
    return cv.u;
#else
    return __builtin_amdgcn_perm(__float_as_uint(b), __float_as_uint(a), 0x07060302u);
#endif
}
__device__ __forceinline__ float fexp2(float x) {
#if __has_builtin(__builtin_amdgcn_exp2f)
    return __builtin_amdgcn_exp2f(x);
#else
    return exp2f(x);
#endif
}
// exp2(relu(x)) — the softmax numerator (temp*log2e folded into q upstream)
__device__ __forceinline__ float er(float x) { return fexp2(fmaxf(x, 0.f)); }

// ---------------- prep: normalize q,k (temp*log2e folded into q); v -> sigma-permuted
// tiles; p==3 slice casts proj_w -> bf16.
// Two spatial columns per thread (float2 loads halve VMEM instr count vs scalar).
// grid (6, 4, NBH), block 192: 6*192*2 = 2304 = NSP.
__global__ __launch_bounds__(192) void prep_kernel(
    const float* __restrict__ qkv, const float* __restrict__ temp,
    const float* __restrict__ projw,
    u16* __restrict__ Qn, u16* __restrict__ Kn, u16* __restrict__ Vp,
    u16* __restrict__ Wb)
{
    const int p  = blockIdx.y;
    const int bh = blockIdx.z, b = bh >> 3, head = bh & 7;

    if (p == 3) {   // proj_w cast: 16384 float4 chunks spread over 6*32 blocks
        const int idx = (bh * 6 + blockIdx.x) * 192 + threadIdx.x;
        if (idx < NCH * NCH / 4) {
            float4 v = ((const float4*)projw)[idx];
            ((uint2*)Wb)[idx] = make_uint2(pack2(v.x, v.y), pack2(v.z, v.w));
        }
        return;
    }

    const int i  = blockIdx.x * 192 + threadIdx.x;   // [0, 1152)
    const int n0 = i * 2;                            // even spatial index; pair (n0, n0+1)
    const float* src = qkv + ((size_t)(b * 3 * NCH + p * NCH + head * HD)) * NSP + n0;

    float2 v[HD];
#pragma unroll
    for (int d = 0; d < HD; ++d) v[d] = *(const float2*)(src + (size_t)d * NSP);

    if (p == 2) {
        // V tile layout: Vp[bh][kt][d*64 + c*32 + quad*8 + jj]; for even n0 the pair
        // (n0, n0+1) maps to adjacent u16 slots -> one aligned u32 store.
        const int tile = n0 >> 6, loc = n0 & 63;
        const int c = loc >> 5, r5 = loc & 31;
        const int qd  = (r5 < 16) ? (r5 >> 2) : ((r5 - 16) >> 2);
        const int jj  = (r5 < 16) ? (r5 & 3) : (4 + (r5 & 3));
        u16* dst = Vp + (size_t)bh * NSP * HD + (size_t)tile * 2048 + c * 32 + qd * 8 + jj;
#pragma unroll
        for (int d = 0; d < HD; ++d) *(u32*)(dst + d * 64) = pack2(v[d].x, v[d].y);
    } else {
        float s0 = 0.f, s1 = 0.f;
#pragma unroll
        for (int d = 0; d < HD; ++d) { s0 += v[d].x * v[d].x; s1 += v[d].y * v[d].y; }
        float sc0 = 1.f / fmaxf(sqrtf(s0), 1e-12f);
        float sc1 = 1.f / fmaxf(sqrtf(s1), 1e-12f);
        if (p == 0) {   // fold temp*log2e into q
            const float t = temp[head] * 1.44269504088896f;
            sc0 *= t; sc1 *= t;
        }
        u32 pk[HD];   // [0..15] row n0, [16..31] row n0+1
#pragma unroll
        for (int j = 0; j < HD / 2; ++j) pk[j]          = pack2(v[2 * j].x * sc0, v[2 * j + 1].x * sc0);
#pragma unroll
        for (int j = 0; j < HD / 2; ++j) pk[HD / 2 + j] = pack2(v[2 * j].y * sc1, v[2 * j + 1].y * sc1);
        u16* dst = (p == 0 ? Qn : Kn) + ((size_t)bh * NSP + n0) * HD;   // 2 rows = 128 B contiguous
#pragma unroll
        for (int j = 0; j < 8; ++j) ((uint4*)dst)[j] = ((const uint4*)pk)[j];
    }
}

// ---------------- flash attention: 64 q-rows/wave, 4-way k-split, barrier-free K-loop ----
// block = 256 thr (4 waves), grid (NBH, NSP/64). blockIdx.x = bh so all q-blocks of a bh
// share one XCD -> K/V L2-resident.
// All 4 waves own the SAME 64 q-rows (t2=4 ILP chains); wave w covers k-tiles [w*9,w*9+9).
// OCCUPANCY PLAN (r0-r3 evidence): r0/r2 (~168 unified regs) -> 3 blk/CU -> 1152 blocks
// run in TWO scheduling rounds (2 x ~27us = 54-55us). r3's 5-blk/CU tier was one round
// but broke per-wave structure (2x VMEM, ILP 2) -> 70us. This version keeps the r2
// structure and diets to <=128 unified regs for 4 blk/CU (1024 co-resident, ~1.125
// effective rounds):
//   - rowsum via MFMA-with-ones (16 AGPR + 72 MFMA/wave) -> 4 scalar fp32 partials
//     (lane sums its 16 exp values; cross-quad shfl_xor after K-loop; 4 shfl
//     redistributes in epilogue). Denominator = sum of fp32 e (vs bf16-rounded):
//     rel shift ~2^-9/sqrt(2304) ~ 4e-6, negligible.
//   - per-c-half inner body (2 S-MFMA -> 8 exp -> pack -> 2 PV): transient peak
//     sf16+pk8 -> ~14 regs. t2-level ILP preserved.
//   - __launch_bounds__(256,4) pins the 128-reg budget (r1's hint failed because
//     demand was ~40 over; now demand ~budget -> no spills expected. Spill telltale:
//     WRITE_SIZE >> 4608 KB).
__global__ __launch_bounds__(256, 4) void attn_kernel(
    const u16* __restrict__ Qn, const u16* __restrict__ Kn,
    const u16* __restrict__ Vp, u16* __restrict__ X)
{
    __shared__ float cmb[4][64][25];   // [wave][lane][tt*12 + {8 O0,O1 | 1 rs}] pad 25
    const int bh = blockIdx.x, b = bh >> 3, head = bh & 7;
    const int w = threadIdx.x >> 6, lane = threadIdx.x & 63;
    const int l15 = lane & 15, quad = lane >> 4;
    const int qbase = blockIdx.y * 64;

    const u16* Kg = Kn + (size_t)bh * NSP * HD + (size_t)w * KPW * 2048 + l15 * HD + quad * 8;
    const u16* Vg = Vp + (size_t)bh * NSP * HD + (size_t)w * KPW * 2048 + l15 * 64 + quad * 8;

    short8 qf[4];
#pragma unroll
    for (int t2 = 0; t2 < 4; ++t2)
        qf[t2] = *(const short8*)(Qn + ((size_t)bh * NSP + qbase + t2 * 16 + l15) * HD + quad * 8);

    const f32x4 zf = {0.f, 0.f, 0.f, 0.f};

    f32x4 oacc[4][2] = {{{0,0,0,0},{0,0,0,0}},{{0,0,0,0},{0,0,0,0}},
                        {{0,0,0,0},{0,0,0,0}},{{0,0,0,0},{0,0,0,0}}};
    float rs[4] = {0.f, 0.f, 0.f, 0.f};   // per-lane rowsum partial (q=l15, lane's k rows)

    // preload K tile 0
    short8 ka[4];
#pragma unroll
    for (int i = 0; i < 4; ++i) ka[i] = *(const short8*)(Kg + i * 512);

    for (int kt = 0; kt < KPW; ++kt) {
        // V for THIS tile: consumed only after S-MFMA+exp chain (latency self-hiding)
        short8 vb[2][2];
#pragma unroll
        for (int c = 0; c < 2; ++c)
#pragma unroll
            for (int h = 0; h < 2; ++h)
                vb[c][h] = *(const short8*)(Vg + (size_t)kt * 2048 + h * 1024 + c * 32);
        // K for NEXT tile
        short8 kan[4];
        if (kt + 1 < KPW) {
            const u16* Kp2 = Kg + (size_t)(kt + 1) * 2048;
#pragma unroll
            for (int i = 0; i < 4; ++i) kan[i] = *(const short8*)(Kp2 + i * 512);
        }

#pragma unroll
        for (int t2 = 0; t2 < 4; ++t2) {
#pragma unroll
            for (int c = 0; c < 2; ++c) {
                const f32x4 s0 = __builtin_amdgcn_mfma_f32_16x16x32_bf16(ka[2 * c],     qf[t2], zf, 0, 0, 0);
                const f32x4 s1 = __builtin_amdgcn_mfma_f32_16x16x32_bf16(ka[2 * c + 1], qf[t2], zf, 0, 0, 0);
                const float e0 = er(s0[0]), e1 = er(s0[1]), e2 = er(s0[2]), e3 = er(s0[3]);
                const float e4 = er(s1[0]), e5 = er(s1[1]), e6 = er(s1[2]), e7 = er(s1[3]);
                rs[t2] += ((e0 + e1) + (e2 + e3)) + ((e4 + e5) + (e6 + e7));
                union { short8 s; u32 u[4]; } pa;
                pa.u[0] = pkfast(e0, e1);
                pa.u[1] = pkfast(e2, e3);
                pa.u[2] = pkfast(e4, e5);
                pa.u[3] = pkfast(e6, e7);
                oacc[t2][0] = __builtin_amdgcn_mfma_f32_16x16x32_bf16(pa.s, vb[c][0], oacc[t2][0], 0, 0, 0);
                oacc[t2][1] = __builtin_amdgcn_mfma_f32_16x16x32_bf16(pa.s, vb[c][1], oacc[t2][1], 0, 0, 0);
            }
        }

        if (kt + 1 < KPW) {
#pragma unroll
            for (int i = 0; i < 4; ++i) ka[i] = kan[i];
        }
    }

    // cross-quad reduce: rs[t2] -> full rowsum over wave's k-range for q=l15
    // (replicated across the 4 quads).
#pragma unroll
    for (int t2 = 0; t2 < 4; ++t2) {
        rs[t2] += __shfl_xor(rs[t2], 16, 64);
        rs[t2] += __shfl_xor(rs[t2], 32, 64);
    }

    // two-phase epilogue: pass 0 handles t2={0,1} (reducers: waves 0,1),
    // pass 1 handles t2={2,3} (reducers: waves 2,3). Reducer wave w always owns t2==w.
#pragma unroll
    for (int pass = 0; pass < 2; ++pass) {
        if (pass) __syncthreads();   // protect cmb overwrite until pass-0 reducers done
        {
            float* my = &cmb[w][lane][0];
#pragma unroll
            for (int tt = 0; tt < 2; ++tt) {
                const int t2 = pass * 2 + tt;
#pragma unroll
                for (int h = 0; h < 2; ++h)
#pragma unroll
                    for (int r = 0; r < 4; ++r) my[tt * 12 + h * 4 + r] = oacc[t2][h][r];
                my[tt * 12 + 8] = rs[t2];
            }
        }
        __syncthreads();
        if ((w >> 1) == pass) {
            const int t2 = w;            // == pass*2 + (w&1)
            const int tt = w & 1;
            float o0[4], o1[4];
            float rq = 0.f;              // rowsum for q=l15, summed over the 4 waves
#pragma unroll
            for (int r = 0; r < 4; ++r) { o0[r] = 0.f; o1[r] = 0.f; }
#pragma unroll
            for (int j = 0; j < 4; ++j) {
                const float* srcp = &cmb[j][lane][tt * 12];
#pragma unroll
                for (int r = 0; r < 4; ++r) {
                    o0[r] += srcp[r];
                    o1[r] += srcp[4 + r];
                }
                rq += srcp[8];
            }
            u16* Xb = X + (size_t)b * NSP * NCH + head * HD;
#pragma unroll
            for (int r = 0; r < 4; ++r) {
                // output row r is q = quad*4 + r; fetch its rowsum from the lane
                // (same quad) whose l15 == quad*4+r.
                const float rsum = __shfl(rq, (lane & 48) + quad * 4 + r, 64);
                const float inv = 1.f / rsum;
                u16* row = Xb + (size_t)(qbase + t2 * 16 + quad * 4 + r) * NCH;
                row[l15]      = f2bf(o0[r] * inv);
                row[16 + l15] = f2bf(o1[r] * inv);
            }
        }
    }
}

// ---------------- 1x1 conv: out[b,o,n] = sum_c W[o,c] X[b,n,c] + bias[o] ----------------
// grid (NSP/32, NCH/64, NB), block 256 (4 waves): wave w does o-tile blockIdx.y*64+w*16,
// all 4 waves share the same 32-row X tile -> L1 reuse.
__global__ __launch_bounds__(256) void proj_kernel(
    const u16* __restrict__ Wb, const u16* __restrict__ X,
    const float* __restrict__ bias, float* __restrict__ out)
{
    const int b = blockIdx.z;
    const int w = threadIdx.x >> 6, lane = threadIdx.x & 63;
    const int l15 = lane & 15, quad = lane >> 4;
    const int obase = blockIdx.y * 64 + w * 16;
    const int nbase = blockIdx.x * 32;

    const u16* wrow = Wb + (size_t)(obase + l15) * NCH + quad * 8;
    const u16* xrow = X + ((size_t)b * NSP + nbase + l15) * NCH + quad * 8;

    f32x4 acc[2] = {{0,0,0,0},{0,0,0,0}};
#pragma unroll
    for (int ks = 0; ks < 8; ++ks) {
        const short8 af = *(const short8*)(wrow + ks * 32);
        acc[0] = __builtin_amdgcn_mfma_f32_16x16x32_bf16(af, *(const short8*)(xrow + ks * 32), acc[0], 0, 0, 0);
        acc[1] = __builtin_amdgcn_mfma_f32_16x16x32_bf16(af, *(const short8*)(xrow + (size_t)16 * NCH + ks * 32), acc[1], 0, 0, 0);
    }
#pragma unroll
    for (int r = 0; r < 4; ++r) {
        const int o = obase + quad * 4 + r;
        const float bo = bias[o];
        float* orow = out + ((size_t)b * NCH + o) * NSP + nbase;
        orow[l15]      = acc[0][r] + bo;
        orow[16 + l15] = acc[1][r] + bo;
    }
}

extern "C" void kernel_launch(void* const* d_in, const int* in_sizes, int n_in,
                              void* d_out, int out_size, void* d_ws, size_t ws_size,
                              hipStream_t stream) {
    const float* qkv   = (const float*)d_in[0];
    const float* temp  = (const float*)d_in[1];
    const float* projw = (const float*)d_in[2];
    const float* projb = (const float*)d_in[3];
    float* out = (float*)d_out;

    // workspace: Qn | Kn | Vp | X (each 2,359,296 bf16) | Wb (65,536 bf16)  ~19 MB
    u16* Qn = (u16*)d_ws;
    u16* Kn = Qn + (size_t)NBH * NSP * HD;
    u16* Vp = Kn + (size_t)NBH * NSP * HD;
    u16* X  = Vp + (size_t)NBH * NSP * HD;
    u16* Wb = X + (size_t)NB * NSP * NCH;

    prep_kernel<<<dim3(6, 4, NBH), dim3(192), 0, stream>>>(qkv, temp, projw, Qn, Kn, Vp, Wb);
    attn_kernel<<<dim3(NBH, NSP / 64), dim3(256), 0, stream>>>(Qn, Kn, Vp, X);
    proj_kernel<<<dim3(NSP / 32, NCH / 64, NB), dim3(256), 0, stream>>>(Wb, X, projb, out);
}

// Round 5
// 159.756 us; speedup vs baseline: 1.2212x; 1.2212x over previous
//
#include <hip/hip_runtime.h>

typedef unsigned short u16;
typedef unsigned int   u32;
typedef __attribute__((ext_vector_type(8))) short short8;   // 8 bf16 = 4 VGPRs
typedef __attribute__((ext_vector_type(4))) float f32x4;

#define NB    4      // batch
#define NCH   256    // channels
#define NHD   8      // heads
#define HD    32     // head dim
#define NSP   2304   // H*W
#define NBH   32     // NB*NHD
#define NKT   36     // total 64-wide K tiles
#define KPW   9      // K tiles per wave (4-wave in-block k-split)

// round-to-nearest-even fp32 -> bf16 bits
__device__ __forceinline__ u16 f2bf(float f) {
    u32 u = __float_as_uint(f);
    u += 0x7FFFu + ((u >> 16) & 1u);
    return (u16)(u >> 16);
}
__device__ __forceinline__ u32 pack2(float a, float b) {
    return (u32)f2bf(a) | ((u32)f2bf(b) << 16);
}
// fast pack two fp32 -> bf16x2: hw cvt (RNE) if present, else 1-instr v_perm truncate.
__device__ __forceinline__ u32 pkfast(float a, float b) {
#if __has_builtin(__builtin_amdgcn_cvt_pk_bf16_f32)
    typedef __attribute__((ext_vector_type(2))) __bf16 bf2;
    union { bf2 v; u32 u; } cv;
    cv.v = __builtin_amdgcn_cvt_pk_bf16_f32(a, b);
    return cv.u;
#else
    return __builtin_amdgcn_perm(__float_as_uint(b), __float_as_uint(a), 0x07060302u);
#endif
}
__device__ __forceinline__ float fexp2(float x) {
#if __has_builtin(__builtin_amdgcn_exp2f)
    return __builtin_amdgcn_exp2f(x);
#else
    return exp2f(x);
#endif
}
// exp2(relu(x)) — the softmax numerator (temp*log2e folded into q upstream)
__device__ __forceinline__ float er(float x) { return fexp2(fmaxf(x, 0.f)); }

// ---------------- prep: normalize q,k (temp*log2e folded into q); v -> sigma-permuted
// tiles; p==3 slice casts proj_w -> bf16.
// Two spatial columns per thread (float2 loads halve VMEM instr count vs scalar).
// grid (6, 4, NBH), block 192: 6*192*2 = 2304 = NSP.
__global__ __launch_bounds__(192) void prep_kernel(
    const float* __restrict__ qkv, const float* __restrict__ temp,
    const float* __restrict__ projw,
    u16* __restrict__ Qn, u16* __restrict__ Kn, u16* __restrict__ Vp,
    u16* __restrict__ Wb)
{
    const int p  = blockIdx.y;
    const int bh = blockIdx.z, b = bh >> 3, head = bh & 7;

    if (p == 3) {   // proj_w cast: 16384 float4 chunks spread over 6*32 blocks
        const int idx = (bh * 6 + blockIdx.x) * 192 + threadIdx.x;
        if (idx < NCH * NCH / 4) {
            float4 v = ((const float4*)projw)[idx];
            ((uint2*)Wb)[idx] = make_uint2(pack2(v.x, v.y), pack2(v.z, v.w));
        }
        return;
    }

    const int i  = blockIdx.x * 192 + threadIdx.x;   // [0, 1152)
    const int n0 = i * 2;                            // even spatial index; pair (n0, n0+1)
    const float* src = qkv + ((size_t)(b * 3 * NCH + p * NCH + head * HD)) * NSP + n0;

    float2 v[HD];
#pragma unroll
    for (int d = 0; d < HD; ++d) v[d] = *(const float2*)(src + (size_t)d * NSP);

    if (p == 2) {
        // V tile layout: Vp[bh][kt][d*64 + c*32 + quad*8 + jj]; for even n0 the pair
        // (n0, n0+1) maps to adjacent u16 slots -> one aligned u32 store.
        const int tile = n0 >> 6, loc = n0 & 63;
        const int c = loc >> 5, r5 = loc & 31;
        const int qd  = (r5 < 16) ? (r5 >> 2) : ((r5 - 16) >> 2);
        const int jj  = (r5 < 16) ? (r5 & 3) : (4 + (r5 & 3));
        u16* dst = Vp + (size_t)bh * NSP * HD + (size_t)tile * 2048 + c * 32 + qd * 8 + jj;
#pragma unroll
        for (int d = 0; d < HD; ++d) *(u32*)(dst + d * 64) = pack2(v[d].x, v[d].y);
    } else {
        float s0 = 0.f, s1 = 0.f;
#pragma unroll
        for (int d = 0; d < HD; ++d) { s0 += v[d].x * v[d].x; s1 += v[d].y * v[d].y; }
        float sc0 = 1.f / fmaxf(sqrtf(s0), 1e-12f);
        float sc1 = 1.f / fmaxf(sqrtf(s1), 1e-12f);
        if (p == 0) {   // fold temp*log2e into q
            const float t = temp[head] * 1.44269504088896f;
            sc0 *= t; sc1 *= t;
        }
        u32 pk[HD];   // [0..15] row n0, [16..31] row n0+1
#pragma unroll
        for (int j = 0; j < HD / 2; ++j) pk[j]          = pack2(v[2 * j].x * sc0, v[2 * j + 1].x * sc0);
#pragma unroll
        for (int j = 0; j < HD / 2; ++j) pk[HD / 2 + j] = pack2(v[2 * j].y * sc1, v[2 * j + 1].y * sc1);
        u16* dst = (p == 0 ? Qn : Kn) + ((size_t)bh * NSP + n0) * HD;   // 2 rows = 128 B contiguous
#pragma unroll
        for (int j = 0; j < 8; ++j) ((uint4*)dst)[j] = ((const uint4*)pk)[j];
    }
}

// ---------------- flash attention: 32 q-rows/block, 4-way k-split, barrier-free K-loop --
// block = 256 thr (4 waves), grid (NBH, NSP/32). blockIdx.x = bh (gridDim.x = 32 == 0 mod
// 8, so linear%8 == bh%8) -> all q-blocks of a bh share one XCD -> K/V L2-resident
// (4 bh/XCD x 295KB = 1.2MB < 4MiB).
// REGISTER-TIER PLAN (r0-r4 evidence): tiers step at total regs (arch+acc) <= 512/w.
// r0's t2=4 structure = ~168 regs = 3 waves/SIMD, two-round schedule -> 54us floor.
// Forcing 128 via hint spilled both times (demand really is 168). r3's k-split-2 got
// the tier but broke VMEM/ILP. THIS version cuts t2 4->2 (qf 8, oacc 16, rsac 8:
// ~116-124 total) -> 4 waves/SIMD NATURALLY, while keeping r0's 4-way k-split
// (1x VMEM/wave-tile) and MFMA-rowsum (keeps rowsum off the busy VALU pipe).
// Grid doubles to 2304 blocks; 4 blk/CU -> 16 waves/CU during full rounds.
// All 4 waves own the SAME 32 q-rows (t2=2 chains); wave w covers k-tiles [w*9,w*9+9).
// Partials combine linearly (exp(relu)/sum: no running max) -> single-pass epilogue:
// wave (t2=w&1, half=w>>1) reduces one 16-col half of one q-tile.
__global__ __launch_bounds__(256) void attn_kernel(
    const u16* __restrict__ Qn, const u16* __restrict__ Kn,
    const u16* __restrict__ Vp, u16* __restrict__ X)
{
    __shared__ float cmb[4][64][25];   // [wave][lane][tt*12 + {8 O0,O1 | 4 rs}] pad 25
    const int bh = blockIdx.x, b = bh >> 3, head = bh & 7;
    const int w = threadIdx.x >> 6, lane = threadIdx.x & 63;
    const int l15 = lane & 15, quad = lane >> 4;
    const int qbase = blockIdx.y * 32;

    const u16* Kg = Kn + (size_t)bh * NSP * HD + (size_t)w * KPW * 2048 + l15 * HD + quad * 8;
    const u16* Vg = Vp + (size_t)bh * NSP * HD + (size_t)w * KPW * 2048 + l15 * 64 + quad * 8;

    short8 qf[2];
#pragma unroll
    for (int t2 = 0; t2 < 2; ++t2)
        qf[t2] = *(const short8*)(Qn + ((size_t)bh * NSP + qbase + t2 * 16 + l15) * HD + quad * 8);

    const short one = (short)0x3F80;   // bf16 1.0
    const short8 vones = {one, one, one, one, one, one, one, one};
    const f32x4 zf = {0.f, 0.f, 0.f, 0.f};

    f32x4 oacc[2][2] = {{{0,0,0,0},{0,0,0,0}},{{0,0,0,0},{0,0,0,0}}};
    f32x4 rsac[2]    = {{0,0,0,0},{0,0,0,0}};

    // preload K tile 0
    short8 ka[4];
#pragma unroll
    for (int i = 0; i < 4; ++i) ka[i] = *(const short8*)(Kg + i * 512);

    for (int kt = 0; kt < KPW; ++kt) {
        // V for THIS tile: consumed only after S-MFMA+exp chain (latency self-hiding)
        short8 vb[2][2];
#pragma unroll
        for (int c = 0; c < 2; ++c)
#pragma unroll
            for (int h = 0; h < 2; ++h)
                vb[c][h] = *(const short8*)(Vg + (size_t)kt * 2048 + h * 1024 + c * 32);
        // K for NEXT tile
        short8 kan[4];
        if (kt + 1 < KPW) {
            const u16* Kp2 = Kg + (size_t)(kt + 1) * 2048;
#pragma unroll
            for (int i = 0; i < 4; ++i) kan[i] = *(const short8*)(Kp2 + i * 512);
        }

#pragma unroll
        for (int t2 = 0; t2 < 2; ++t2) {
            f32x4 sf[4];
#pragma unroll
            for (int i = 0; i < 4; ++i)
                sf[i] = __builtin_amdgcn_mfma_f32_16x16x32_bf16(ka[i], qf[t2], zf, 0, 0, 0);
            u32 pk[4][2];
#pragma unroll
            for (int i = 0; i < 4; ++i) {
                pk[i][0] = pkfast(er(sf[i][0]), er(sf[i][1]));
                pk[i][1] = pkfast(er(sf[i][2]), er(sf[i][3]));
            }
#pragma unroll
            for (int c = 0; c < 2; ++c) {
                union { short8 s; u32 u[4]; } pa;
                pa.u[0] = pk[2 * c][0];     pa.u[1] = pk[2 * c][1];
                pa.u[2] = pk[2 * c + 1][0]; pa.u[3] = pk[2 * c + 1][1];
                oacc[t2][0] = __builtin_amdgcn_mfma_f32_16x16x32_bf16(pa.s, vb[c][0], oacc[t2][0], 0, 0, 0);
                oacc[t2][1] = __builtin_amdgcn_mfma_f32_16x16x32_bf16(pa.s, vb[c][1], oacc[t2][1], 0, 0, 0);
                rsac[t2]    = __builtin_amdgcn_mfma_f32_16x16x32_bf16(pa.s, vones,    rsac[t2],    0, 0, 0);
            }
        }

        if (kt + 1 < KPW) {
#pragma unroll
            for (int i = 0; i < 4; ++i) ka[i] = kan[i];
        }
    }

    // single-pass epilogue: each wave publishes its 2 q-tile partials (24 floats/lane);
    // then wave w reduces column-half (w>>1) of q-tile (w&1) across the 4 publishers.
    {
        float* my = &cmb[w][lane][0];
#pragma unroll
        for (int tt = 0; tt < 2; ++tt) {
#pragma unroll
            for (int h = 0; h < 2; ++h)
#pragma unroll
                for (int r = 0; r < 4; ++r) my[tt * 12 + h * 4 + r] = oacc[tt][h][r];
#pragma unroll
            for (int r = 0; r < 4; ++r) my[tt * 12 + 8 + r] = rsac[tt][r];
        }
    }
    __syncthreads();
    {
        const int t2 = w & 1;        // q-tile this wave reduces
        const int hh = w >> 1;       // column half (0: cols 0-15, 1: cols 16-31)
        float o[4] = {0.f, 0.f, 0.f, 0.f}, rsum[4] = {0.f, 0.f, 0.f, 0.f};
#pragma unroll
        for (int j = 0; j < 4; ++j) {
            const float* srcp = &cmb[j][lane][t2 * 12];
#pragma unroll
            for (int r = 0; r < 4; ++r) {
                o[r]    += srcp[hh * 4 + r];
                rsum[r] += srcp[8 + r];
            }
        }
        u16* Xb = X + (size_t)b * NSP * NCH + head * HD;
#pragma unroll
        for (int r = 0; r < 4; ++r) {
            const float inv = 1.f / rsum[r];
            u16* row = Xb + (size_t)(qbase + t2 * 16 + quad * 4 + r) * NCH;
            row[hh * 16 + l15] = f2bf(o[r] * inv);
        }
    }
}

// ---------------- 1x1 conv: out[b,o,n] = sum_c W[o,c] X[b,n,c] + bias[o] ----------------
// grid (NSP/32, NCH/64, NB), block 256 (4 waves): wave w does o-tile blockIdx.y*64+w*16,
// all 4 waves share the same 32-row X tile -> L1 reuse.
__global__ __launch_bounds__(256) void proj_kernel(
    const u16* __restrict__ Wb, const u16* __restrict__ X,
    const float* __restrict__ bias, float* __restrict__ out)
{
    const int b = blockIdx.z;
    const int w = threadIdx.x >> 6, lane = threadIdx.x & 63;
    const int l15 = lane & 15, quad = lane >> 4;
    const int obase = blockIdx.y * 64 + w * 16;
    const int nbase = blockIdx.x * 32;

    const u16* wrow = Wb + (size_t)(obase + l15) * NCH + quad * 8;
    const u16* xrow = X + ((size_t)b * NSP + nbase + l15) * NCH + quad * 8;

    f32x4 acc[2] = {{0,0,0,0},{0,0,0,0}};
#pragma unroll
    for (int ks = 0; ks < 8; ++ks) {
        const short8 af = *(const short8*)(wrow + ks * 32);
        acc[0] = __builtin_amdgcn_mfma_f32_16x16x32_bf16(af, *(const short8*)(xrow + ks * 32), acc[0], 0, 0, 0);
        acc[1] = __builtin_amdgcn_mfma_f32_16x16x32_bf16(af, *(const short8*)(xrow + (size_t)16 * NCH + ks * 32), acc[1], 0, 0, 0);
    }
#pragma unroll
    for (int r = 0; r < 4; ++r) {
        const int o = obase + quad * 4 + r;
        const float bo = bias[o];
        float* orow = out + ((size_t)b * NCH + o) * NSP + nbase;
        orow[l15]      = acc[0][r] + bo;
        orow[16 + l15] = acc[1][r] + bo;
    }
}

extern "C" void kernel_launch(void* const* d_in, const int* in_sizes, int n_in,
                              void* d_out, int out_size, void* d_ws, size_t ws_size,
                              hipStream_t stream) {
    const float* qkv   = (const float*)d_in[0];
    const float* temp  = (const float*)d_in[1];
    const float* projw = (const float*)d_in[2];
    const float* projb = (const float*)d_in[3];
    float* out = (float*)d_out;

    // workspace: Qn | Kn | Vp | X (each 2,359,296 bf16) | Wb (65,536 bf16)  ~19 MB
    u16* Qn = (u16*)d_ws;
    u16* Kn = Qn + (size_t)NBH * NSP * HD;
    u16* Vp = Kn + (size_t)NBH * NSP * HD;
    u16* X  = Vp + (size_t)NBH * NSP * HD;
    u16* Wb = X + (size_t)NB * NSP * NCH;

    prep_kernel<<<dim3(6, 4, NBH), dim3(192), 0, stream>>>(qkv, temp, projw, Qn, Kn, Vp, Wb);
    attn_kernel<<<dim3(NBH, NSP / 32), dim3(256), 0, stream>>>(Qn, Kn, Vp, X);
    proj_kernel<<<dim3(NSP / 32, NCH / 64, NB), dim3(256), 0, stream>>>(Wb, X, projb, out);
}

// Round 6
// 148.578 us; speedup vs baseline: 1.3131x; 1.0752x over previous
//
#include <hip/hip_runtime.h>

typedef unsigned short u16;
typedef unsigned int   u32;
typedef __attribute__((ext_vector_type(8))) short short8;   // 8 bf16 = 4 VGPRs
typedef __attribute__((ext_vector_type(4))) float f32x4;

#define NB    4      // batch
#define NCH   256    // channels
#define NHD   8      // heads
#define HD    32     // head dim
#define NSP   2304   // H*W
#define NBH   32     // NB*NHD
#define NKT   36     // total 64-wide K tiles
#define KPW   9      // K tiles per wave (4-wave in-block k-split)

// round-to-nearest-even fp32 -> bf16 bits
__device__ __forceinline__ u16 f2bf(float f) {
    u32 u = __float_as_uint(f);
    u += 0x7FFFu + ((u >> 16) & 1u);
    return (u16)(u >> 16);
}
__device__ __forceinline__ u32 pack2(float a, float b) {
    return (u32)f2bf(a) | ((u32)f2bf(b) << 16);
}
// fast pack two fp32 -> bf16x2: hw cvt (RNE) if present, else 1-instr v_perm truncate.
__device__ __forceinline__ u32 pkfast(float a, float b) {
#if __has_builtin(__builtin_amdgcn_cvt_pk_bf16_f32)
    typedef __attribute__((ext_vector_type(2))) __bf16 bf2;
    union { bf2 v; u32 u; } cv;
    cv.v = __builtin_amdgcn_cvt_pk_bf16_f32(a, b);
    return cv.u;
#else
    return __builtin_amdgcn_perm(__float_as_uint(b), __float_as_uint(a), 0x07060302u);
#endif
}
__device__ __forceinline__ float fexp2(float x) {
#if __has_builtin(__builtin_amdgcn_exp2f)
    return __builtin_amdgcn_exp2f(x);
#else
    return exp2f(x);
#endif
}
// exp2(relu(x)) — the softmax numerator (temp*log2e folded into q upstream)
__device__ __forceinline__ float er(float x) { return fexp2(fmaxf(x, 0.f)); }

// ---------------- prep: normalize q,k (temp*log2e folded into q); v -> sigma-permuted
// tiles; p==3 slice casts proj_w -> bf16.
// Two spatial columns per thread (float2 loads halve VMEM instr count vs scalar).
// grid (6, 4, NBH), block 192: 6*192*2 = 2304 = NSP.
__global__ __launch_bounds__(192) void prep_kernel(
    const float* __restrict__ qkv, const float* __restrict__ temp,
    const float* __restrict__ projw,
    u16* __restrict__ Qn, u16* __restrict__ Kn, u16* __restrict__ Vp,
    u16* __restrict__ Wb)
{
    const int p  = blockIdx.y;
    const int bh = blockIdx.z, b = bh >> 3, head = bh & 7;

    if (p == 3) {   // proj_w cast: 16384 float4 chunks spread over 6*32 blocks
        const int idx = (bh * 6 + blockIdx.x) * 192 + threadIdx.x;
        if (idx < NCH * NCH / 4) {
            float4 v = ((const float4*)projw)[idx];
            ((uint2*)Wb)[idx] = make_uint2(pack2(v.x, v.y), pack2(v.z, v.w));
        }
        return;
    }

    const int i  = blockIdx.x * 192 + threadIdx.x;   // [0, 1152)
    const int n0 = i * 2;                            // even spatial index; pair (n0, n0+1)
    const float* src = qkv + ((size_t)(b * 3 * NCH + p * NCH + head * HD)) * NSP + n0;

    float2 v[HD];
#pragma unroll
    for (int d = 0; d < HD; ++d) v[d] = *(const float2*)(src + (size_t)d * NSP);

    if (p == 2) {
        // V tile layout: Vp[bh][kt][d*64 + c*32 + quad*8 + jj]; for even n0 the pair
        // (n0, n0+1) maps to adjacent u16 slots -> one aligned u32 store.
        const int tile = n0 >> 6, loc = n0 & 63;
        const int c = loc >> 5, r5 = loc & 31;
        const int qd  = (r5 < 16) ? (r5 >> 2) : ((r5 - 16) >> 2);
        const int jj  = (r5 < 16) ? (r5 & 3) : (4 + (r5 & 3));
        u16* dst = Vp + (size_t)bh * NSP * HD + (size_t)tile * 2048 + c * 32 + qd * 8 + jj;
#pragma unroll
        for (int d = 0; d < HD; ++d) *(u32*)(dst + d * 64) = pack2(v[d].x, v[d].y);
    } else {
        float s0 = 0.f, s1 = 0.f;
#pragma unroll
        for (int d = 0; d < HD; ++d) { s0 += v[d].x * v[d].x; s1 += v[d].y * v[d].y; }
        float sc0 = 1.f / fmaxf(sqrtf(s0), 1e-12f);
        float sc1 = 1.f / fmaxf(sqrtf(s1), 1e-12f);
        if (p == 0) {   // fold temp*log2e into q
            const float t = temp[head] * 1.44269504088896f;
            sc0 *= t; sc1 *= t;
        }
        u32 pk[HD];   // [0..15] row n0, [16..31] row n0+1
#pragma unroll
        for (int j = 0; j < HD / 2; ++j) pk[j]          = pack2(v[2 * j].x * sc0, v[2 * j + 1].x * sc0);
#pragma unroll
        for (int j = 0; j < HD / 2; ++j) pk[HD / 2 + j] = pack2(v[2 * j].y * sc1, v[2 * j + 1].y * sc1);
        u16* dst = (p == 0 ? Qn : Kn) + ((size_t)bh * NSP + n0) * HD;   // 2 rows = 128 B contiguous
#pragma unroll
        for (int j = 0; j < 8; ++j) ((uint4*)dst)[j] = ((const uint4*)pk)[j];
    }
}

// ---------------- flash attention: 64 q-rows/wave, 4-way k-split, barrier-free K-loop ----
// block = 256 thr (4 waves), grid (NBH, NSP/64). blockIdx.x = bh so all q-blocks of a bh
// share one XCD -> K/V L2-resident.
// STRUCTURE (settled by r0-r5): t2=4 ILP chains per wave, 4-way k-split (1x VMEM), MFMA
// rowsum, ~168 unified regs -> 3 waves/SIMD. All occupancy-raising variants (t2=2 with
// k-split 2 or 4, forced 128-reg hints) LOST: per-wave ILP dominates residency here.
// r6 adds two register-neutral K-loop refinements:
//  (1) kt-loop unrolled x2 with role-swapped K buffers (ka/kb) -> kills the 16 v_mov
//      ka<-kan copies per kt (~300 VALU cyc/wave on the busiest pipe).
//  (2) s_setprio(1) around MFMA clusters only (S and PV/rs) — matches the measured
//      attention-with-independent-waves win case (m191, +4-7%), not the lockstep-GEMM
//      null case (our K-loop is barrier-free).
__device__ __forceinline__ void kbody(
    const u16* __restrict__ Kg, const u16* __restrict__ Vg, int kt, bool pf,
    short8 (&kc)[4], short8 (&kn)[4], const short8 (&qf)[4],
    f32x4 (&oacc)[4][2], f32x4 (&rsac)[4])
{
    const short one = (short)0x3F80;   // bf16 1.0
    const short8 vones = {one, one, one, one, one, one, one, one};
    const f32x4 zf = {0.f, 0.f, 0.f, 0.f};

    // V for THIS tile: consumed only after S-MFMA+exp chain (latency self-hiding)
    short8 vb[2][2];
#pragma unroll
    for (int c = 0; c < 2; ++c)
#pragma unroll
        for (int h = 0; h < 2; ++h)
            vb[c][h] = *(const short8*)(Vg + (size_t)kt * 2048 + h * 1024 + c * 32);
    // K for NEXT tile into the other role buffer (no copy-back)
    if (pf) {
#pragma unroll
        for (int i = 0; i < 4; ++i)
            kn[i] = *(const short8*)(Kg + (size_t)(kt + 1) * 2048 + i * 512);
    }

#pragma unroll
    for (int t2 = 0; t2 < 4; ++t2) {
        f32x4 sf[4];
        __builtin_amdgcn_s_setprio(1);
#pragma unroll
        for (int i = 0; i < 4; ++i)
            sf[i] = __builtin_amdgcn_mfma_f32_16x16x32_bf16(kc[i], qf[t2], zf, 0, 0, 0);
        __builtin_amdgcn_s_setprio(0);
        u32 pk[4][2];
#pragma unroll
        for (int i = 0; i < 4; ++i) {
            pk[i][0] = pkfast(er(sf[i][0]), er(sf[i][1]));
            pk[i][1] = pkfast(er(sf[i][2]), er(sf[i][3]));
        }
#pragma unroll
        for (int c = 0; c < 2; ++c) {
            union { short8 s; u32 u[4]; } pa;
            pa.u[0] = pk[2 * c][0];     pa.u[1] = pk[2 * c][1];
            pa.u[2] = pk[2 * c + 1][0]; pa.u[3] = pk[2 * c + 1][1];
            __builtin_amdgcn_s_setprio(1);
            oacc[t2][0] = __builtin_amdgcn_mfma_f32_16x16x32_bf16(pa.s, vb[c][0], oacc[t2][0], 0, 0, 0);
            oacc[t2][1] = __builtin_amdgcn_mfma_f32_16x16x32_bf16(pa.s, vb[c][1], oacc[t2][1], 0, 0, 0);
            rsac[t2]    = __builtin_amdgcn_mfma_f32_16x16x32_bf16(pa.s, vones,    rsac[t2],    0, 0, 0);
            __builtin_amdgcn_s_setprio(0);
        }
    }
}

__global__ __launch_bounds__(256) void attn_kernel(
    const u16* __restrict__ Qn, const u16* __restrict__ Kn,
    const u16* __restrict__ Vp, u16* __restrict__ X)
{
    __shared__ float cmb[4][64][49];   // [wave][lane][t2*12 + {8 O0,O1 | 4 rs}] pad 49
    const int bh = blockIdx.x, b = bh >> 3, head = bh & 7;
    const int w = threadIdx.x >> 6, lane = threadIdx.x & 63;
    const int l15 = lane & 15, quad = lane >> 4;
    const int qbase = blockIdx.y * 64;

    const u16* Kg = Kn + (size_t)bh * NSP * HD + (size_t)w * KPW * 2048 + l15 * HD + quad * 8;
    const u16* Vg = Vp + (size_t)bh * NSP * HD + (size_t)w * KPW * 2048 + l15 * 64 + quad * 8;

    short8 qf[4];
#pragma unroll
    for (int t2 = 0; t2 < 4; ++t2)
        qf[t2] = *(const short8*)(Qn + ((size_t)bh * NSP + qbase + t2 * 16 + l15) * HD + quad * 8);

    f32x4 oacc[4][2] = {{{0,0,0,0},{0,0,0,0}},{{0,0,0,0},{0,0,0,0}},
                        {{0,0,0,0},{0,0,0,0}},{{0,0,0,0},{0,0,0,0}}};
    f32x4 rsac[4]    = {{0,0,0,0},{0,0,0,0},{0,0,0,0},{0,0,0,0}};

    // preload K tile 0 into ka; ka/kb alternate roles (current/prefetch) per body
    short8 ka[4], kb[4];
#pragma unroll
    for (int i = 0; i < 4; ++i) ka[i] = *(const short8*)(Kg + i * 512);

    // KPW=9: pairs (0,1)(2,3)(4,5)(6,7) + peeled tail 8. Body(kt) consumes its K buffer
    // and prefetches K(kt+1) into the OTHER buffer — no copy-back moves.
    for (int kt = 0; kt < KPW - 1; kt += 2) {
        kbody(Kg, Vg, kt,     true,  ka, kb, qf, oacc, rsac);
        kbody(Kg, Vg, kt + 1, true,  kb, ka, qf, oacc, rsac);
    }
    kbody(Kg, Vg, KPW - 1, false, ka, kb, qf, oacc, rsac);

    // publish all partials; wave w reduces + writes q-tile t2 == w
    {
        float* my = &cmb[w][lane][0];
#pragma unroll
        for (int t2 = 0; t2 < 4; ++t2) {
#pragma unroll
            for (int h = 0; h < 2; ++h)
#pragma unroll
                for (int r = 0; r < 4; ++r) my[t2 * 12 + h * 4 + r] = oacc[t2][h][r];
#pragma unroll
            for (int r = 0; r < 4; ++r) my[t2 * 12 + 8 + r] = rsac[t2][r];
        }
    }
    __syncthreads();
    {
        const int t2 = w;
        float o0[4] = {0,0,0,0}, o1[4] = {0,0,0,0}, rsum[4] = {0,0,0,0};
#pragma unroll
        for (int j = 0; j < 4; ++j) {
            const float* srcp = &cmb[j][lane][t2 * 12];
#pragma unroll
            for (int r = 0; r < 4; ++r) {
                o0[r]   += srcp[r];
                o1[r]   += srcp[4 + r];
                rsum[r] += srcp[8 + r];
            }
        }
        u16* Xb = X + (size_t)b * NSP * NCH + head * HD;
#pragma unroll
        for (int r = 0; r < 4; ++r) {
            const float inv = 1.f / rsum[r];
            u16* row = Xb + (size_t)(qbase + t2 * 16 + quad * 4 + r) * NCH;
            row[l15]      = f2bf(o0[r] * inv);
            row[16 + l15] = f2bf(o1[r] * inv);
        }
    }
}

// ---------------- 1x1 conv: out[b,o,n] = sum_c W[o,c] X[b,n,c] + bias[o] ----------------
// grid (NSP/32, NCH/64, NB), block 256 (4 waves): wave w does o-tile blockIdx.y*64+w*16,
// all 4 waves share the same 32-row X tile -> L1 reuse.
__global__ __launch_bounds__(256) void proj_kernel(
    const u16* __restrict__ Wb, const u16* __restrict__ X,
    const float* __restrict__ bias, float* __restrict__ out)
{
    const int b = blockIdx.z;
    const int w = threadIdx.x >> 6, lane = threadIdx.x & 63;
    const int l15 = lane & 15, quad = lane >> 4;
    const int obase = blockIdx.y * 64 + w * 16;
    const int nbase = blockIdx.x * 32;

    const u16* wrow = Wb + (size_t)(obase + l15) * NCH + quad * 8;
    const u16* xrow = X + ((size_t)b * NSP + nbase + l15) * NCH + quad * 8;

    f32x4 acc[2] = {{0,0,0,0},{0,0,0,0}};
#pragma unroll
    for (int ks = 0; ks < 8; ++ks) {
        const short8 af = *(const short8*)(wrow + ks * 32);
        acc[0] = __builtin_amdgcn_mfma_f32_16x16x32_bf16(af, *(const short8*)(xrow + ks * 32), acc[0], 0, 0, 0);
        acc[1] = __builtin_amdgcn_mfma_f32_16x16x32_bf16(af, *(const short8*)(xrow + (size_t)16 * NCH + ks * 32), acc[1], 0, 0, 0);
    }
#pragma unroll
    for (int r = 0; r < 4; ++r) {
        const int o = obase + quad * 4 + r;
        const float bo = bias[o];
        float* orow = out + ((size_t)b * NCH + o) * NSP + nbase;
        orow[l15]      = acc[0][r] + bo;
        orow[16 + l15] = acc[1][r] + bo;
    }
}

extern "C" void kernel_launch(void* const* d_in, const int* in_sizes, int n_in,
                              void* d_out, int out_size, void* d_ws, size_t ws_size,
                              hipStream_t stream) {
    const float* qkv   = (const float*)d_in[0];
    const float* temp  = (const float*)d_in[1];
    const float* projw = (const float*)d_in[2];
    const float* projb = (const float*)d_in[3];
    float* out = (float*)d_out;

    // workspace: Qn | Kn | Vp | X (each 2,359,296 bf16) | Wb (65,536 bf16)  ~19 MB
    u16* Qn = (u16*)d_ws;
    u16* Kn = Qn + (size_t)NBH * NSP * HD;
    u16* Vp = Kn + (size_t)NBH * NSP * HD;
    u16* X  = Vp + (size_t)NBH * NSP * HD;
    u16* Wb = X + (size_t)NB * NSP * NCH;

    prep_kernel<<<dim3(6, 4, NBH), dim3(192), 0, stream>>>(qkv, temp, projw, Qn, Kn, Vp, Wb);
    attn_kernel<<<dim3(NBH, NSP / 64), dim3(256), 0, stream>>>(Qn, Kn, Vp, X);
    proj_kernel<<<dim3(NSP / 32, NCH / 64, NB), dim3(256), 0, stream>>>(Wb, X, projb, out);
}

// Round 7
// 148.350 us; speedup vs baseline: 1.3151x; 1.0015x over previous
//
#include <hip/hip_runtime.h>

typedef unsigned short u16;
typedef unsigned int   u32;
typedef __attribute__((ext_vector_type(8))) short short8;   // 8 bf16 = 4 VGPRs
typedef __attribute__((ext_vector_type(4))) float f32x4;

#define NB    4      // batch
#define NCH   256    // channels
#define NHD   8      // heads
#define HD    32     // head dim
#define NSP   2304   // H*W
#define NBH   32     // NB*NHD
#define NKT   36     // total 64-wide K tiles
#define KPW   9      // K tiles per wave (4-wave in-block k-split)

// round-to-nearest-even fp32 -> bf16 bits
__device__ __forceinline__ u16 f2bf(float f) {
    u32 u = __float_as_uint(f);
    u += 0x7FFFu + ((u >> 16) & 1u);
    return (u16)(u >> 16);
}
__device__ __forceinline__ u32 pack2(float a, float b) {
    return (u32)f2bf(a) | ((u32)f2bf(b) << 16);
}
// fast pack two fp32 -> bf16x2: hw cvt (RNE) if present, else 1-instr v_perm truncate.
__device__ __forceinline__ u32 pkfast(float a, float b) {
#if __has_builtin(__builtin_amdgcn_cvt_pk_bf16_f32)
    typedef __attribute__((ext_vector_type(2))) __bf16 bf2;
    union { bf2 v; u32 u; } cv;
    cv.v = __builtin_amdgcn_cvt_pk_bf16_f32(a, b);
    return cv.u;
#else
    return __builtin_amdgcn_perm(__float_as_uint(b), __float_as_uint(a), 0x07060302u);
#endif
}
__device__ __forceinline__ float fexp2(float x) {
#if __has_builtin(__builtin_amdgcn_exp2f)
    return __builtin_amdgcn_exp2f(x);
#else
    return exp2f(x);
#endif
}
// exp2(relu(x)) — the softmax numerator (temp*log2e folded into q upstream)
__device__ __forceinline__ float er(float x) { return fexp2(fmaxf(x, 0.f)); }

// ---------------- prep: normalize q,k (temp*log2e folded into q); v -> sigma-permuted
// tiles; p==3 slice casts proj_w -> bf16.
// Two spatial columns per thread (float2 loads halve VMEM instr count vs scalar).
// grid (6, 4, NBH), block 192: 6*192*2 = 2304 = NSP.
__global__ __launch_bounds__(192) void prep_kernel(
    const float* __restrict__ qkv, const float* __restrict__ temp,
    const float* __restrict__ projw,
    u16* __restrict__ Qn, u16* __restrict__ Kn, u16* __restrict__ Vp,
    u16* __restrict__ Wb)
{
    const int p  = blockIdx.y;
    const int bh = blockIdx.z, b = bh >> 3, head = bh & 7;

    if (p == 3) {   // proj_w cast: 16384 float4 chunks spread over 6*32 blocks
        const int idx = (bh * 6 + blockIdx.x) * 192 + threadIdx.x;
        if (idx < NCH * NCH / 4) {
            float4 v = ((const float4*)projw)[idx];
            ((uint2*)Wb)[idx] = make_uint2(pack2(v.x, v.y), pack2(v.z, v.w));
        }
        return;
    }

    const int i  = blockIdx.x * 192 + threadIdx.x;   // [0, 1152)
    const int n0 = i * 2;                            // even spatial index; pair (n0, n0+1)
    const float* src = qkv + ((size_t)(b * 3 * NCH + p * NCH + head * HD)) * NSP + n0;

    float2 v[HD];
#pragma unroll
    for (int d = 0; d < HD; ++d) v[d] = *(const float2*)(src + (size_t)d * NSP);

    if (p == 2) {
        // V tile layout: Vp[bh][kt][d*64 + c*32 + quad*8 + jj]; for even n0 the pair
        // (n0, n0+1) maps to adjacent u16 slots -> one aligned u32 store.
        const int tile = n0 >> 6, loc = n0 & 63;
        const int c = loc >> 5, r5 = loc & 31;
        const int qd  = (r5 < 16) ? (r5 >> 2) : ((r5 - 16) >> 2);
        const int jj  = (r5 < 16) ? (r5 & 3) : (4 + (r5 & 3));
        u16* dst = Vp + (size_t)bh * NSP * HD + (size_t)tile * 2048 + c * 32 + qd * 8 + jj;
#pragma unroll
        for (int d = 0; d < HD; ++d) *(u32*)(dst + d * 64) = pack2(v[d].x, v[d].y);
    } else {
        float s0 = 0.f, s1 = 0.f;
#pragma unroll
        for (int d = 0; d < HD; ++d) { s0 += v[d].x * v[d].x; s1 += v[d].y * v[d].y; }
        float sc0 = 1.f / fmaxf(sqrtf(s0), 1e-12f);
        float sc1 = 1.f / fmaxf(sqrtf(s1), 1e-12f);
        if (p == 0) {   // fold temp*log2e into q
            const float t = temp[head] * 1.44269504088896f;
            sc0 *= t; sc1 *= t;
        }
        u32 pk[HD];   // [0..15] row n0, [16..31] row n0+1
#pragma unroll
        for (int j = 0; j < HD / 2; ++j) pk[j]          = pack2(v[2 * j].x * sc0, v[2 * j + 1].x * sc0);
#pragma unroll
        for (int j = 0; j < HD / 2; ++j) pk[HD / 2 + j] = pack2(v[2 * j].y * sc1, v[2 * j + 1].y * sc1);
        u16* dst = (p == 0 ? Qn : Kn) + ((size_t)bh * NSP + n0) * HD;   // 2 rows = 128 B contiguous
#pragma unroll
        for (int j = 0; j < 8; ++j) ((uint4*)dst)[j] = ((const uint4*)pk)[j];
    }
}

// ---------------- flash attention: 64 q-rows/wave, 4-way k-split, barrier-free K-loop ----
// block = 256 thr (4 waves), grid (NBH, NSP/64). blockIdx.x = bh so all q-blocks of a bh
// share one XCD -> K/V L2-resident.
// STRUCTURE (settled by r0-r6): t2=4 ILP chains per wave, 4-way k-split (1x VMEM), MFMA
// rowsum, ~156 unified regs -> 3 waves/SIMD. All occupancy-raising variants LOST (r3,r5);
// issue-quality micro-opts WIN (r6: role-swap K prefetch + setprio = 54.1 -> 52.0 us).
// r7: extend the ping-pong prefetch to V (was loaded at top of the body that consumes
// it, ~200cyc L2 latency only partially hidden under the S/exp chain; now loaded one
// full body ahead, ~700cyc cover). +16 VGPR, stays inside the 3-wave tier (<=170).
__device__ __forceinline__ void kbody(
    const u16* __restrict__ Kg, const u16* __restrict__ Vg, int kt, bool pf,
    short8 (&kc)[4], short8 (&kn)[4],
    short8 (&vc)[2][2], short8 (&vn)[2][2],
    const short8 (&qf)[4],
    f32x4 (&oacc)[4][2], f32x4 (&rsac)[4])
{
    const short one = (short)0x3F80;   // bf16 1.0
    const short8 vones = {one, one, one, one, one, one, one, one};
    const f32x4 zf = {0.f, 0.f, 0.f, 0.f};

    // prefetch K and V for NEXT tile into the other role buffers (no copy-back)
    if (pf) {
#pragma unroll
        for (int i = 0; i < 4; ++i)
            kn[i] = *(const short8*)(Kg + (size_t)(kt + 1) * 2048 + i * 512);
#pragma unroll
        for (int c = 0; c < 2; ++c)
#pragma unroll
            for (int h = 0; h < 2; ++h)
                vn[c][h] = *(const short8*)(Vg + (size_t)(kt + 1) * 2048 + h * 1024 + c * 32);
    }

#pragma unroll
    for (int t2 = 0; t2 < 4; ++t2) {
        f32x4 sf[4];
        __builtin_amdgcn_s_setprio(1);
#pragma unroll
        for (int i = 0; i < 4; ++i)
            sf[i] = __builtin_amdgcn_mfma_f32_16x16x32_bf16(kc[i], qf[t2], zf, 0, 0, 0);
        __builtin_amdgcn_s_setprio(0);
        u32 pk[4][2];
#pragma unroll
        for (int i = 0; i < 4; ++i) {
            pk[i][0] = pkfast(er(sf[i][0]), er(sf[i][1]));
            pk[i][1] = pkfast(er(sf[i][2]), er(sf[i][3]));
        }
#pragma unroll
        for (int c = 0; c < 2; ++c) {
            union { short8 s; u32 u[4]; } pa;
            pa.u[0] = pk[2 * c][0];     pa.u[1] = pk[2 * c][1];
            pa.u[2] = pk[2 * c + 1][0]; pa.u[3] = pk[2 * c + 1][1];
            __builtin_amdgcn_s_setprio(1);
            oacc[t2][0] = __builtin_amdgcn_mfma_f32_16x16x32_bf16(pa.s, vc[c][0], oacc[t2][0], 0, 0, 0);
            oacc[t2][1] = __builtin_amdgcn_mfma_f32_16x16x32_bf16(pa.s, vc[c][1], oacc[t2][1], 0, 0, 0);
            rsac[t2]    = __builtin_amdgcn_mfma_f32_16x16x32_bf16(pa.s, vones,    rsac[t2],    0, 0, 0);
            __builtin_amdgcn_s_setprio(0);
        }
    }
}

__global__ __launch_bounds__(256) void attn_kernel(
    const u16* __restrict__ Qn, const u16* __restrict__ Kn,
    const u16* __restrict__ Vp, u16* __restrict__ X)
{
    __shared__ float cmb[4][64][49];   // [wave][lane][t2*12 + {8 O0,O1 | 4 rs}] pad 49
    const int bh = blockIdx.x, b = bh >> 3, head = bh & 7;
    const int w = threadIdx.x >> 6, lane = threadIdx.x & 63;
    const int l15 = lane & 15, quad = lane >> 4;
    const int qbase = blockIdx.y * 64;

    const u16* Kg = Kn + (size_t)bh * NSP * HD + (size_t)w * KPW * 2048 + l15 * HD + quad * 8;
    const u16* Vg = Vp + (size_t)bh * NSP * HD + (size_t)w * KPW * 2048 + l15 * 64 + quad * 8;

    short8 qf[4];
#pragma unroll
    for (int t2 = 0; t2 < 4; ++t2)
        qf[t2] = *(const short8*)(Qn + ((size_t)bh * NSP + qbase + t2 * 16 + l15) * HD + quad * 8);

    f32x4 oacc[4][2] = {{{0,0,0,0},{0,0,0,0}},{{0,0,0,0},{0,0,0,0}},
                        {{0,0,0,0},{0,0,0,0}},{{0,0,0,0},{0,0,0,0}}};
    f32x4 rsac[4]    = {{0,0,0,0},{0,0,0,0},{0,0,0,0},{0,0,0,0}};

    // preload K and V tile 0 into the 'a' role buffers; a/b alternate per body
    short8 ka[4], kb[4];
    short8 va[2][2], vb[2][2];
#pragma unroll
    for (int i = 0; i < 4; ++i) ka[i] = *(const short8*)(Kg + i * 512);
#pragma unroll
    for (int c = 0; c < 2; ++c)
#pragma unroll
        for (int h = 0; h < 2; ++h)
            va[c][h] = *(const short8*)(Vg + h * 1024 + c * 32);

    // KPW=9: pairs (0,1)(2,3)(4,5)(6,7) + peeled tail 8. Body(kt) consumes its K/V
    // buffers and prefetches tile kt+1 into the OTHER buffers — no copy-back moves.
    for (int kt = 0; kt < KPW - 1; kt += 2) {
        kbody(Kg, Vg, kt,     true,  ka, kb, va, vb, qf, oacc, rsac);
        kbody(Kg, Vg, kt + 1, true,  kb, ka, vb, va, qf, oacc, rsac);
    }
    kbody(Kg, Vg, KPW - 1, false, ka, kb, va, vb, qf, oacc, rsac);

    // publish all partials; wave w reduces + writes q-tile t2 == w
    {
        float* my = &cmb[w][lane][0];
#pragma unroll
        for (int t2 = 0; t2 < 4; ++t2) {
#pragma unroll
            for (int h = 0; h < 2; ++h)
#pragma unroll
                for (int r = 0; r < 4; ++r) my[t2 * 12 + h * 4 + r] = oacc[t2][h][r];
#pragma unroll
            for (int r = 0; r < 4; ++r) my[t2 * 12 + 8 + r] = rsac[t2][r];
        }
    }
    __syncthreads();
    {
        const int t2 = w;
        float o0[4] = {0,0,0,0}, o1[4] = {0,0,0,0}, rsum[4] = {0,0,0,0};
#pragma unroll
        for (int j = 0; j < 4; ++j) {
            const float* srcp = &cmb[j][lane][t2 * 12];
#pragma unroll
            for (int r = 0; r < 4; ++r) {
                o0[r]   += srcp[r];
                o1[r]   += srcp[4 + r];
                rsum[r] += srcp[8 + r];
            }
        }
        u16* Xb = X + (size_t)b * NSP * NCH + head * HD;
#pragma unroll
        for (int r = 0; r < 4; ++r) {
            const float inv = 1.f / rsum[r];
            u16* row = Xb + (size_t)(qbase + t2 * 16 + quad * 4 + r) * NCH;
            row[l15]      = f2bf(o0[r] * inv);
            row[16 + l15] = f2bf(o1[r] * inv);
        }
    }
}

// ---------------- 1x1 conv: out[b,o,n] = sum_c W[o,c] X[b,n,c] + bias[o] ----------------
// grid (NSP/32, NCH/64, NB), block 256 (4 waves): wave w does o-tile blockIdx.y*64+w*16,
// all 4 waves share the same 32-row X tile -> L1 reuse.
__global__ __launch_bounds__(256) void proj_kernel(
    const u16* __restrict__ Wb, const u16* __restrict__ X,
    const float* __restrict__ bias, float* __restrict__ out)
{
    const int b = blockIdx.z;
    const int w = threadIdx.x >> 6, lane = threadIdx.x & 63;
    const int l15 = lane & 15, quad = lane >> 4;
    const int obase = blockIdx.y * 64 + w * 16;
    const int nbase = blockIdx.x * 32;

    const u16* wrow = Wb + (size_t)(obase + l15) * NCH + quad * 8;
    const u16* xrow = X + ((size_t)b * NSP + nbase + l15) * NCH + quad * 8;

    f32x4 acc[2] = {{0,0,0,0},{0,0,0,0}};
#pragma unroll
    for (int ks = 0; ks < 8; ++ks) {
        const short8 af = *(const short8*)(wrow + ks * 32);
        acc[0] = __builtin_amdgcn_mfma_f32_16x16x32_bf16(af, *(const short8*)(xrow + ks * 32), acc[0], 0, 0, 0);
        acc[1] = __builtin_amdgcn_mfma_f32_16x16x32_bf16(af, *(const short8*)(xrow + (size_t)16 * NCH + ks * 32), acc[1], 0, 0, 0);
    }
#pragma unroll
    for (int r = 0; r < 4; ++r) {
        const int o = obase + quad * 4 + r;
        const float bo = bias[o];
        float* orow = out + ((size_t)b * NCH + o) * NSP + nbase;
        orow[l15]      = acc[0][r] + bo;
        orow[16 + l15] = acc[1][r] + bo;
    }
}

extern "C" void kernel_launch(void* const* d_in, const int* in_sizes, int n_in,
                              void* d_out, int out_size, void* d_ws, size_t ws_size,
                              hipStream_t stream) {
    const float* qkv   = (const float*)d_in[0];
    const float* temp  = (const float*)d_in[1];
    const float* projw = (const float*)d_in[2];
    const float* projb = (const float*)d_in[3];
    float* out = (float*)d_out;

    // workspace: Qn | Kn | Vp | X (each 2,359,296 bf16) | Wb (65,536 bf16)  ~19 MB
    u16* Qn = (u16*)d_ws;
    u16* Kn = Qn + (size_t)NBH * NSP * HD;
    u16* Vp = Kn + (size_t)NBH * NSP * HD;
    u16* X  = Vp + (size_t)NBH * NSP * HD;
    u16* Wb = X + (size_t)NB * NSP * NCH;

    prep_kernel<<<dim3(6, 4, NBH), dim3(192), 0, stream>>>(qkv, temp, projw, Qn, Kn, Vp, Wb);
    attn_kernel<<<dim3(NBH, NSP / 64), dim3(256), 0, stream>>>(Qn, Kn, Vp, X);
    proj_kernel<<<dim3(NSP / 32, NCH / 64, NB), dim3(256), 0, stream>>>(Wb, X, projb, out);
}

// Round 8
// 147.056 us; speedup vs baseline: 1.3267x; 1.0088x over previous
//
#include <hip/hip_runtime.h>

typedef unsigned short u16;
typedef unsigned int   u32;
typedef __attribute__((ext_vector_type(8))) short short8;   // 8 bf16 = 4 VGPRs
typedef __attribute__((ext_vector_type(4))) float f32x4;

#define NB    4      // batch
#define NCH   256    // channels
#define NHD   8      // heads
#define HD    32     // head dim
#define NSP   2304   // H*W
#define NBH   32     // NB*NHD
#define NKT   36     // total 64-wide K tiles
#define KPW   9      // K tiles per wave (4-wave in-block k-split)

// round-to-nearest-even fp32 -> bf16 bits
__device__ __forceinline__ u16 f2bf(float f) {
    u32 u = __float_as_uint(f);
    u += 0x7FFFu + ((u >> 16) & 1u);
    return (u16)(u >> 16);
}
__device__ __forceinline__ u32 pack2(float a, float b) {
    return (u32)f2bf(a) | ((u32)f2bf(b) << 16);
}
// fast pack two fp32 -> bf16x2: hw cvt (RNE) if present, else 1-instr v_perm truncate.
__device__ __forceinline__ u32 pkfast(float a, float b) {
#if __has_builtin(__builtin_amdgcn_cvt_pk_bf16_f32)
    typedef __attribute__((ext_vector_type(2))) __bf16 bf2;
    union { bf2 v; u32 u; } cv;
    cv.v = __builtin_amdgcn_cvt_pk_bf16_f32(a, b);
    return cv.u;
#else
    return __builtin_amdgcn_perm(__float_as_uint(b), __float_as_uint(a), 0x07060302u);
#endif
}
__device__ __forceinline__ float fexp2(float x) {
#if __has_builtin(__builtin_amdgcn_exp2f)
    return __builtin_amdgcn_exp2f(x);
#else
    return exp2f(x);
#endif
}
// exp2(relu(x)) — the softmax numerator (temp*log2e folded into q upstream)
__device__ __forceinline__ float er(float x) { return fexp2(fmaxf(x, 0.f)); }

// ---------------- prep: normalize q,k (temp*log2e folded into q); v -> sigma-permuted
// tiles; p==3 slice casts proj_w -> bf16.
// Two spatial columns per thread (float2 loads halve VMEM instr count vs scalar).
// grid (6, 4, NBH), block 192: 6*192*2 = 2304 = NSP.
__global__ __launch_bounds__(192) void prep_kernel(
    const float* __restrict__ qkv, const float* __restrict__ temp,
    const float* __restrict__ projw,
    u16* __restrict__ Qn, u16* __restrict__ Kn, u16* __restrict__ Vp,
    u16* __restrict__ Wb)
{
    const int p  = blockIdx.y;
    const int bh = blockIdx.z, b = bh >> 3, head = bh & 7;

    if (p == 3) {   // proj_w cast: 16384 float4 chunks spread over 6*32 blocks
        const int idx = (bh * 6 + blockIdx.x) * 192 + threadIdx.x;
        if (idx < NCH * NCH / 4) {
            float4 v = ((const float4*)projw)[idx];
            ((uint2*)Wb)[idx] = make_uint2(pack2(v.x, v.y), pack2(v.z, v.w));
        }
        return;
    }

    const int i  = blockIdx.x * 192 + threadIdx.x;   // [0, 1152)
    const int n0 = i * 2;                            // even spatial index; pair (n0, n0+1)
    const float* src = qkv + ((size_t)(b * 3 * NCH + p * NCH + head * HD)) * NSP + n0;

    float2 v[HD];
#pragma unroll
    for (int d = 0; d < HD; ++d) v[d] = *(const float2*)(src + (size_t)d * NSP);

    if (p == 2) {
        // V tile layout: Vp[bh][kt][d*64 + c*32 + quad*8 + jj]; for even n0 the pair
        // (n0, n0+1) maps to adjacent u16 slots -> one aligned u32 store.
        const int tile = n0 >> 6, loc = n0 & 63;
        const int c = loc >> 5, r5 = loc & 31;
        const int qd  = (r5 < 16) ? (r5 >> 2) : ((r5 - 16) >> 2);
        const int jj  = (r5 < 16) ? (r5 & 3) : (4 + (r5 & 3));
        u16* dst = Vp + (size_t)bh * NSP * HD + (size_t)tile * 2048 + c * 32 + qd * 8 + jj;
#pragma unroll
        for (int d = 0; d < HD; ++d) *(u32*)(dst + d * 64) = pack2(v[d].x, v[d].y);
    } else {
        float s0 = 0.f, s1 = 0.f;
#pragma unroll
        for (int d = 0; d < HD; ++d) { s0 += v[d].x * v[d].x; s1 += v[d].y * v[d].y; }
        float sc0 = 1.f / fmaxf(sqrtf(s0), 1e-12f);
        float sc1 = 1.f / fmaxf(sqrtf(s1), 1e-12f);
        if (p == 0) {   // fold temp*log2e into q
            const float t = temp[head] * 1.44269504088896f;
            sc0 *= t; sc1 *= t;
        }
        u32 pk[HD];   // [0..15] row n0, [16..31] row n0+1
#pragma unroll
        for (int j = 0; j < HD / 2; ++j) pk[j]          = pack2(v[2 * j].x * sc0, v[2 * j + 1].x * sc0);
#pragma unroll
        for (int j = 0; j < HD / 2; ++j) pk[HD / 2 + j] = pack2(v[2 * j].y * sc1, v[2 * j + 1].y * sc1);
        u16* dst = (p == 0 ? Qn : Kn) + ((size_t)bh * NSP + n0) * HD;   // 2 rows = 128 B contiguous
#pragma unroll
        for (int j = 0; j < 8; ++j) ((uint4*)dst)[j] = ((const uint4*)pk)[j];
    }
}

// ---------------- flash attention: 64 q-rows/wave, 4-way k-split, barrier-free K-loop ----
// block = 256 thr (4 waves), grid (NBH, NSP/64). blockIdx.x = bh so all q-blocks of a bh
// share one XCD -> K/V L2-resident.
// STRUCTURE (settled r0-r7): t2=4 chains/wave, 4-way k-split, MFMA rowsum, ping-pong
// K+V prefetch, ~160 unified regs -> 3 waves/SIMD. Occupancy-buying variants LOST
// (r3,r5); V-prefetch null (r7) -> VMEM latency covered.
// r8: (1) REMOVE s_setprio — LLVM treats side-effecting intrinsics as scheduling-region
// boundaries; the r6 pairs carved the body into tiny regions pinning the serialized
// S->exp->PV order per t2 (the measured setprio win, m191, was a different 1-wave
// structure). (2) Lag-1 software pipeline: issue S-MFMAs of t2+1, then exp/pack/PV of
// t2 in the same unfenced region -> VALU/trans chain of tile t2 overlaps MFMA issue of
// t2+1. +16 transient VGPR (sfA+sfB live) stays inside the 3-wave tier (<=170).
__device__ __forceinline__ void sblock(const short8 (&kc)[4], const short8& q, f32x4 (&sf)[4]) {
    const f32x4 zf = {0.f, 0.f, 0.f, 0.f};
#pragma unroll
    for (int i = 0; i < 4; ++i)
        sf[i] = __builtin_amdgcn_mfma_f32_16x16x32_bf16(kc[i], q, zf, 0, 0, 0);
}
__device__ __forceinline__ void finish(const f32x4 (&sf)[4], const short8 (&vc)[2][2],
                                       f32x4 (&oT)[2], f32x4& rT) {
    const short one = (short)0x3F80;   // bf16 1.0
    const short8 vones = {one, one, one, one, one, one, one, one};
#pragma unroll
    for (int c = 0; c < 2; ++c) {
        union { short8 s; u32 u[4]; } pa;
        pa.u[0] = pkfast(er(sf[2 * c][0]),     er(sf[2 * c][1]));
        pa.u[1] = pkfast(er(sf[2 * c][2]),     er(sf[2 * c][3]));
        pa.u[2] = pkfast(er(sf[2 * c + 1][0]), er(sf[2 * c + 1][1]));
        pa.u[3] = pkfast(er(sf[2 * c + 1][2]), er(sf[2 * c + 1][3]));
        oT[0] = __builtin_amdgcn_mfma_f32_16x16x32_bf16(pa.s, vc[c][0], oT[0], 0, 0, 0);
        oT[1] = __builtin_amdgcn_mfma_f32_16x16x32_bf16(pa.s, vc[c][1], oT[1], 0, 0, 0);
        rT    = __builtin_amdgcn_mfma_f32_16x16x32_bf16(pa.s, vones,    rT,    0, 0, 0);
    }
}
__device__ __forceinline__ void kbody(
    const u16* __restrict__ Kg, const u16* __restrict__ Vg, int kt, bool pf,
    short8 (&kc)[4], short8 (&kn)[4],
    short8 (&vc)[2][2], short8 (&vn)[2][2],
    const short8 (&qf)[4],
    f32x4 (&oacc)[4][2], f32x4 (&rsac)[4])
{
    // prefetch K and V for NEXT tile into the other role buffers (no copy-back)
    if (pf) {
#pragma unroll
        for (int i = 0; i < 4; ++i)
            kn[i] = *(const short8*)(Kg + (size_t)(kt + 1) * 2048 + i * 512);
#pragma unroll
        for (int c = 0; c < 2; ++c)
#pragma unroll
            for (int h = 0; h < 2; ++h)
                vn[c][h] = *(const short8*)(Vg + (size_t)(kt + 1) * 2048 + h * 1024 + c * 32);
    }

    // lag-1 pipeline over t2: S(t2+1) issues before finish(t2) consumes sf(t2).
    f32x4 sfA[4], sfB[4];
    sblock(kc, qf[0], sfA);
    sblock(kc, qf[1], sfB);
    finish(sfA, vc, oacc[0], rsac[0]);
    sblock(kc, qf[2], sfA);
    finish(sfB, vc, oacc[1], rsac[1]);
    sblock(kc, qf[3], sfB);
    finish(sfA, vc, oacc[2], rsac[2]);
    finish(sfB, vc, oacc[3], rsac[3]);
}

__global__ __launch_bounds__(256) void attn_kernel(
    const u16* __restrict__ Qn, const u16* __restrict__ Kn,
    const u16* __restrict__ Vp, u16* __restrict__ X)
{
    __shared__ float cmb[4][64][49];   // [wave][lane][t2*12 + {8 O0,O1 | 4 rs}] pad 49
    const int bh = blockIdx.x, b = bh >> 3, head = bh & 7;
    const int w = threadIdx.x >> 6, lane = threadIdx.x & 63;
    const int l15 = lane & 15, quad = lane >> 4;
    const int qbase = blockIdx.y * 64;

    const u16* Kg = Kn + (size_t)bh * NSP * HD + (size_t)w * KPW * 2048 + l15 * HD + quad * 8;
    const u16* Vg = Vp + (size_t)bh * NSP * HD + (size_t)w * KPW * 2048 + l15 * 64 + quad * 8;

    short8 qf[4];
#pragma unroll
    for (int t2 = 0; t2 < 4; ++t2)
        qf[t2] = *(const short8*)(Qn + ((size_t)bh * NSP + qbase + t2 * 16 + l15) * HD + quad * 8);

    f32x4 oacc[4][2] = {{{0,0,0,0},{0,0,0,0}},{{0,0,0,0},{0,0,0,0}},
                        {{0,0,0,0},{0,0,0,0}},{{0,0,0,0},{0,0,0,0}}};
    f32x4 rsac[4]    = {{0,0,0,0},{0,0,0,0},{0,0,0,0},{0,0,0,0}};

    // preload K and V tile 0 into the 'a' role buffers; a/b alternate per body
    short8 ka[4], kb[4];
    short8 va[2][2], vb[2][2];
#pragma unroll
    for (int i = 0; i < 4; ++i) ka[i] = *(const short8*)(Kg + i * 512);
#pragma unroll
    for (int c = 0; c < 2; ++c)
#pragma unroll
        for (int h = 0; h < 2; ++h)
            va[c][h] = *(const short8*)(Vg + h * 1024 + c * 32);

    // KPW=9: pairs (0,1)(2,3)(4,5)(6,7) + peeled tail 8. Body(kt) consumes its K/V
    // buffers and prefetches tile kt+1 into the OTHER buffers — no copy-back moves.
    for (int kt = 0; kt < KPW - 1; kt += 2) {
        kbody(Kg, Vg, kt,     true,  ka, kb, va, vb, qf, oacc, rsac);
        kbody(Kg, Vg, kt + 1, true,  kb, ka, vb, va, qf, oacc, rsac);
    }
    kbody(Kg, Vg, KPW - 1, false, ka, kb, va, vb, qf, oacc, rsac);

    // publish all partials; wave w reduces + writes q-tile t2 == w
    {
        float* my = &cmb[w][lane][0];
#pragma unroll
        for (int t2 = 0; t2 < 4; ++t2) {
#pragma unroll
            for (int h = 0; h < 2; ++h)
#pragma unroll
                for (int r = 0; r < 4; ++r) my[t2 * 12 + h * 4 + r] = oacc[t2][h][r];
#pragma unroll
            for (int r = 0; r < 4; ++r) my[t2 * 12 + 8 + r] = rsac[t2][r];
        }
    }
    __syncthreads();
    {
        const int t2 = w;
        float o0[4] = {0,0,0,0}, o1[4] = {0,0,0,0}, rsum[4] = {0,0,0,0};
#pragma unroll
        for (int j = 0; j < 4; ++j) {
            const float* srcp = &cmb[j][lane][t2 * 12];
#pragma unroll
            for (int r = 0; r < 4; ++r) {
                o0[r]   += srcp[r];
                o1[r]   += srcp[4 + r];
                rsum[r] += srcp[8 + r];
            }
        }
        u16* Xb = X + (size_t)b * NSP * NCH + head * HD;
#pragma unroll
        for (int r = 0; r < 4; ++r) {
            const float inv = 1.f / rsum[r];
            u16* row = Xb + (size_t)(qbase + t2 * 16 + quad * 4 + r) * NCH;
            row[l15]      = f2bf(o0[r] * inv);
            row[16 + l15] = f2bf(o1[r] * inv);
        }
    }
}

// ---------------- 1x1 conv: out[b,o,n] = sum_c W[o,c] X[b,n,c] + bias[o] ----------------
// grid (NSP/32, NCH/64, NB), block 256 (4 waves): wave w does o-tile blockIdx.y*64+w*16,
// all 4 waves share the same 32-row X tile -> L1 reuse.
__global__ __launch_bounds__(256) void proj_kernel(
    const u16* __restrict__ Wb, const u16* __restrict__ X,
    const float* __restrict__ bias, float* __restrict__ out)
{
    const int b = blockIdx.z;
    const int w = threadIdx.x >> 6, lane = threadIdx.x & 63;
    const int l15 = lane & 15, quad = lane >> 4;
    const int obase = blockIdx.y * 64 + w * 16;
    const int nbase = blockIdx.x * 32;

    const u16* wrow = Wb + (size_t)(obase + l15) * NCH + quad * 8;
    const u16* xrow = X + ((size_t)b * NSP + nbase + l15) * NCH + quad * 8;

    f32x4 acc[2] = {{0,0,0,0},{0,0,0,0}};
#pragma unroll
    for (int ks = 0; ks < 8; ++ks) {
        const short8 af = *(const short8*)(wrow + ks * 32);
        acc[0] = __builtin_amdgcn_mfma_f32_16x16x32_bf16(af, *(const short8*)(xrow + ks * 32), acc[0], 0, 0, 0);
        acc[1] = __builtin_amdgcn_mfma_f32_16x16x32_bf16(af, *(const short8*)(xrow + (size_t)16 * NCH + ks * 32), acc[1], 0, 0, 0);
    }
#pragma unroll
    for (int r = 0; r < 4; ++r) {
        const int o = obase + quad * 4 + r;
        const float bo = bias[o];
        float* orow = out + ((size_t)b * NCH + o) * NSP + nbase;
        orow[l15]      = acc[0][r] + bo;
        orow[16 + l15] = acc[1][r] + bo;
    }
}

extern "C" void kernel_launch(void* const* d_in, const int* in_sizes, int n_in,
                              void* d_out, int out_size, void* d_ws, size_t ws_size,
                              hipStream_t stream) {
    const float* qkv   = (const float*)d_in[0];
    const float* temp  = (const float*)d_in[1];
    const float* projw = (const float*)d_in[2];
    const float* projb = (const float*)d_in[3];
    float* out = (float*)d_out;

    // workspace: Qn | Kn | Vp | X (each 2,359,296 bf16) | Wb (65,536 bf16)  ~19 MB
    u16* Qn = (u16*)d_ws;
    u16* Kn = Qn + (size_t)NBH * NSP * HD;
    u16* Vp = Kn + (size_t)NBH * NSP * HD;
    u16* X  = Vp + (size_t)NBH * NSP * HD;
    u16* Wb = X + (size_t)NB * NSP * NCH;

    prep_kernel<<<dim3(6, 4, NBH), dim3(192), 0, stream>>>(qkv, temp, projw, Qn, Kn, Vp, Wb);
    attn_kernel<<<dim3(NBH, NSP / 64), dim3(256), 0, stream>>>(Qn, Kn, Vp, X);
    proj_kernel<<<dim3(NSP / 32, NCH / 64, NB), dim3(256), 0, stream>>>(Wb, X, projb, out);
}